// Round 12
// baseline (140.794 us; speedup 1.0000x reference)
//
#include <hip/hip_runtime.h>
#include <hip/hip_bf16.h>
#include <cstdint>

#define B 32
#define L 512
#define T 2048
#define M 80
#define KDIM 160

#define NEG_INF (-1e30f)
#define LOG_2PI 1.8378770664093453f

typedef uint32_t u32;
typedef unsigned short u16;
typedef u16 u16x8 __attribute__((ext_vector_type(8)));
typedef short bf16x8 __attribute__((ext_vector_type(8)));
typedef float f32x4 __attribute__((ext_vector_type(4)));

// robust to harness passing lengths as int32 or int64 (values are small positive;
// if int64, word[1] == high word of elem0 == 0; if int32, word[1] in [64,2048] != 0)
__device__ __forceinline__ int get_len(const int* __restrict__ p, int b) {
  return (p[1] == 0) ? p[2 * b] : p[b];
}

__device__ __forceinline__ u16 f2bf(float f) {
  __hip_bfloat16 h = __float2bfloat16(f);
  return *(u16*)&h;
}

// ---------------- prep: Wfrag[b][kc][l][8] (bf16 B-fragments), bias[b][l] --------
// k in [0,80):  W = -0.5*inv_var (pairs with x^2); k in [80,160): W = mu*inv_var.
__global__ __launch_bounds__(256) void prep_kernel(const float* __restrict__ mu_sigma,
                                                   u16* __restrict__ Wfrag,
                                                   float* __restrict__ biasv) {
  int gid = blockIdx.x * 256 + threadIdx.x;  // b*L + l
  if (gid >= B * L) return;
  int b = gid >> 9;
  int l = gid & (L - 1);
  const float* row = mu_sigma + (size_t)gid * (2 * M);
  float acc_a = 0.f, acc_ls = 0.f;
#pragma unroll 2
  for (int g = 0; g < 10; ++g) {
    u16x8 wsq, wli;
#pragma unroll
    for (int j = 0; j < 8; ++j) {
      float mu = row[g * 8 + j];
      float ls = row[M + g * 8 + j];
      float iv = expf(-2.f * ls);
      acc_a += mu * mu * iv;
      acc_ls += ls;
      wsq[j] = f2bf(-0.5f * iv);
      wli[j] = f2bf(mu * iv);
    }
    *(u16x8*)(Wfrag + ((size_t)(b * 20 + g) * L + l) * 8) = wsq;
    *(u16x8*)(Wfrag + ((size_t)(b * 20 + 10 + g) * L + l) * 8) = wli;
  }
  biasv[gid] = -0.5f * acc_a - (0.5f * (float)M * LOG_2PI + 0.5f * acc_ls);
}

// ---------------- xprep: Xfrag[b][kc][t][8] (bf16 A-fragments) ----------------
__global__ __launch_bounds__(256) void xprep_kernel(const float* __restrict__ melspec,
                                                    u16* __restrict__ Xfrag) {
  int gid = blockIdx.x * 256 + threadIdx.x;  // (b*10 + mg)*T + t
  int t = gid & (T - 1);
  int rest = gid >> 11;
  int mg = rest % 10;
  int b = rest / 10;
  u16x8 sq, li;
#pragma unroll
  for (int j = 0; j < 8; ++j) {
    float xv = melspec[((size_t)b * M + mg * 8 + j) * T + t];
    sq[j] = f2bf(xv * xv);
    li[j] = f2bf(xv);
  }
  *(u16x8*)(Xfrag + ((size_t)(b * 20 + mg) * T + t) * 8) = sq;
  *(u16x8*)(Xfrag + ((size_t)(b * 20 + 10 + mg) * T + t) * 8) = li;
}

// ---------------- gemm (MFMA): logpT[b][t][l] bf16 = bias + sum_k X*W ----------
__global__ __launch_bounds__(256) void gemm_logp(const u16* __restrict__ Xfrag,
                                                 const u16* __restrict__ Wfrag,
                                                 const float* __restrict__ biasv,
                                                 const int* __restrict__ mel_len,
                                                 const int* __restrict__ text_len,
                                                 u16* __restrict__ logpT,
                                                 int t_begin, int tc) {
  int b = blockIdx.z;
  int t0 = t_begin + blockIdx.x * 64;
  int l0 = blockIdx.y * 128;
  if (t0 >= get_len(mel_len, b)) return;
  if (l0 >= get_len(text_len, b)) return;

  int tid = threadIdx.x;
  int wave = tid >> 6, lane = tid & 63;
  int wt = wave >> 1, wl = wave & 1;
  int mbase = t0 + wt * 32;
  int nbase = l0 + wl * 64;
  int l16 = lane & 15, khalf = lane >> 4;

  const bf16x8* Xp = (const bf16x8*)Xfrag;
  const bf16x8* Wp = (const bf16x8*)Wfrag;

  f32x4 acc[2][4];
#pragma unroll
  for (int i = 0; i < 2; ++i)
#pragma unroll
    for (int j = 0; j < 4; ++j) acc[i][j] = (f32x4){0.f, 0.f, 0.f, 0.f};

#pragma unroll
  for (int ks = 0; ks < 5; ++ks) {
    int kc = ks * 4 + khalf;
    size_t xb = (size_t)(b * 20 + kc) * T;
    size_t wb = (size_t)(b * 20 + kc) * L;
    bf16x8 a0 = Xp[xb + mbase + l16];
    bf16x8 a1 = Xp[xb + mbase + 16 + l16];
    bf16x8 b0 = Wp[wb + nbase + l16];
    bf16x8 b1 = Wp[wb + nbase + 16 + l16];
    bf16x8 b2 = Wp[wb + nbase + 32 + l16];
    bf16x8 b3 = Wp[wb + nbase + 48 + l16];
    acc[0][0] = __builtin_amdgcn_mfma_f32_16x16x32_bf16(a0, b0, acc[0][0], 0, 0, 0);
    acc[0][1] = __builtin_amdgcn_mfma_f32_16x16x32_bf16(a0, b1, acc[0][1], 0, 0, 0);
    acc[0][2] = __builtin_amdgcn_mfma_f32_16x16x32_bf16(a0, b2, acc[0][2], 0, 0, 0);
    acc[0][3] = __builtin_amdgcn_mfma_f32_16x16x32_bf16(a0, b3, acc[0][3], 0, 0, 0);
    acc[1][0] = __builtin_amdgcn_mfma_f32_16x16x32_bf16(a1, b0, acc[1][0], 0, 0, 0);
    acc[1][1] = __builtin_amdgcn_mfma_f32_16x16x32_bf16(a1, b1, acc[1][1], 0, 0, 0);
    acc[1][2] = __builtin_amdgcn_mfma_f32_16x16x32_bf16(a1, b2, acc[1][2], 0, 0, 0);
    acc[1][3] = __builtin_amdgcn_mfma_f32_16x16x32_bf16(a1, b3, acc[1][3], 0, 0, 0);
  }

  // epilogue: C/D map col = lane&15, row = khalf*4 + r  [verified m89/m91]
  int rbase = khalf * 4;
#pragma unroll
  for (int j = 0; j < 4; ++j) {
    int colL = nbase + j * 16 + l16;
    float bias = biasv[b * L + colL];
#pragma unroll
    for (int i = 0; i < 2; ++i) {
#pragma unroll
      for (int r = 0; r < 4; ++r) {
        int t = mbase + i * 16 + rbase + r;
        logpT[((size_t)b * tc + (t - t_begin)) * L + colL] = f2bf(acc[i][j][r] + bias);
      }
    }
  }
}

// ---------------- scan: 7 waves per batch, halo-redundant max-plus ----------------
// Wave w covers cols [64w, 64w+128) (2/lane), owns the top 64 (wave0 all 128);
// halo degrades 1 col/step -> LDS exchange + barrier every 64 steps. 4-block
// register pipeline of named u32 (32 outstanding dword loads); ONE counted
// vmcnt(24)+sched_barrier per 8-row block (loads landed 3 blocks ago), then the
// compiler freely schedules the 8 steps (unpacks hoist; only fmax/add chain is
// serial). DPP wave_shr for the in-wave boundary.
#define GLDW(dst, p, imm) \
  asm volatile("global_load_dword %0, %1, off offset:" #imm : "=v"(dst) : "v"(p))
#define VMW(n)                                             \
  do {                                                     \
    asm volatile("s_waitcnt vmcnt(" #n ")" ::: "memory");  \
    __builtin_amdgcn_sched_barrier(0);                     \
  } while (0)

#define DECL_BLK8(P) u32 P##0, P##1, P##2, P##3, P##4, P##5, P##6, P##7
#define LOAD_BLK8(P, plo_)             \
  do {                                 \
    const char* lo_ = (plo_);          \
    const char* hi_ = lo_ + 4096;      \
    GLDW(P##0, lo_, 0);                \
    GLDW(P##1, lo_, 1024);             \
    GLDW(P##2, lo_, 2048);             \
    GLDW(P##3, lo_, 3072);             \
    GLDW(P##4, hi_, 0);                \
    GLDW(P##5, hi_, 1024);             \
    GLDW(P##6, hi_, 2048);             \
    GLDW(P##7, hi_, 3072);             \
  } while (0)
// one wait per block: 4 blocks x 8 loads in flight = 32; vmcnt(24) retires the
// oldest block. Loads landed ~3 blocks ago so this never actually stalls long.
#define COMP_BLK8(P)       \
  do {                     \
    VMW(24);               \
    stepu(P##0);           \
    stepu(P##1);           \
    stepu(P##2);           \
    stepu(P##3);           \
    stepu(P##4);           \
    stepu(P##5);           \
    stepu(P##6);           \
    stepu(P##7);           \
  } while (0)

__device__ __forceinline__ float dpp_shr1_neginf(float x) {
  int r = __builtin_amdgcn_update_dpp(__float_as_int(NEG_INF), __float_as_int(x),
                                      0x138, 0xf, 0xf, false);  // wave_shr:1
  return __int_as_float(r);
}

__global__ __launch_bounds__(448, 2) void scan_kernel(const u16* __restrict__ logpT,
                                                      const int* __restrict__ mel_len,
                                                      const int* __restrict__ text_len,
                                                      float* __restrict__ carry_ws,
                                                      float* __restrict__ la_ws,
                                                      int t_begin, int tc) {
  __shared__ float smem[2][512];
  int tid = threadIdx.x;
  int wave = tid >> 6;
  int lane = tid & 63;
  int b = blockIdx.x;
  int ml = get_len(mel_len, b);
  int tl = get_len(text_len, b);
  const u16* base0 = logpT + (size_t)b * tc * L;
  const char* laneB = (const char*)base0 + 128 * wave + 4 * lane;
  float* cws = carry_ws + b * L;
  int col0 = 64 * wave + 2 * lane;               // col of c0 (c1 = col0+1)
  bool owner = (wave == 0) || (lane >= 32);      // owns cols col0, col0+1

  float c0, c1;
  int tstart;
  if (t_begin == 0) {
    c0 = NEG_INF; c1 = NEG_INF;
    if (tid == 0) c0 = __uint_as_float((u32)base0[0] << 16);  // logp[b,0,0]
    tstart = 1;
  } else {
    float2 v = *(const float2*)(cws + col0);
    c0 = v.x; c1 = v.y;
    tstart = t_begin;
  }

  int tstop = min(t_begin + tc, ml);
  int sidx = 0;

  auto stepu = [&](u32 v) {
    float p = dpp_shr1_neginf(c1);  // lane-1's old c1; lane0 <- NEG_INF (halo edge)
    float f0 = __uint_as_float(v << 16);
    float f1 = __uint_as_float(v & 0xFFFF0000u);
    c1 = fmaxf(c1, c0) + f1;
    c0 = fmaxf(c0, p) + f0;
  };

  auto dosync = [&]() {  // refresh halos from owners; one barrier, parity dbuf
    int par = sidx & 1;
    ++sidx;
    if (owner) {
      smem[par][col0] = c0;
      smem[par][col0 + 1] = c1;
    }
    __syncthreads();
    if (wave > 0 && lane < 32) {
      c0 = smem[par][col0];
      c1 = smem[par][col0 + 1];
    }
  };

  int nrows = tstop - tstart;
  if (nrows > 0) {
    int nfull = nrows >> 3;
    const char* p0 = laneB + (size_t)(tstart - t_begin) * 1024;
    if (nfull >= 4) {
      const char* pmax = p0 + (size_t)(nfull - 1) * 8192;
      DECL_BLK8(A);
      DECL_BLK8(Bb);
      DECL_BLK8(Cc);
      DECL_BLK8(Dd);
      LOAD_BLK8(A, p0);
      LOAD_BLK8(Bb, p0 + 8192);
      LOAD_BLK8(Cc, p0 + 16384);
      LOAD_BLK8(Dd, p0 + 24576);
      const char* pload = p0 + 4 * 8192;
      if (pload > pmax) pload = pmax;
      int i = 0;
      for (;;) {
        COMP_BLK8(A);
        ++i; if ((i & 7) == 0) dosync();
        if (i == nfull) break;
        LOAD_BLK8(A, pload);
        pload += 8192; if (pload > pmax) pload = pmax;
        COMP_BLK8(Bb);
        ++i; if ((i & 7) == 0) dosync();
        if (i == nfull) break;
        LOAD_BLK8(Bb, pload);
        pload += 8192; if (pload > pmax) pload = pmax;
        COMP_BLK8(Cc);
        ++i; if ((i & 7) == 0) dosync();
        if (i == nfull) break;
        LOAD_BLK8(Cc, pload);
        pload += 8192; if (pload > pmax) pload = pmax;
        COMP_BLK8(Dd);
        ++i; if ((i & 7) == 0) dosync();
        if (i == nfull) break;
        LOAD_BLK8(Dd, pload);
        pload += 8192; if (pload > pmax) pload = pmax;
      }
      asm volatile("s_waitcnt vmcnt(0)" ::: "memory");  // drain dup prefetches
    } else {
      nfull = 0;
    }
    // tail rows (< 8, and whole chunk when nfull < 4; staleness stays < 64)
    for (int t = tstart + (nfull << 3); t < tstop; ++t) {
      u32 v = *(const u32*)(laneB + (size_t)(t - t_begin) * 1024);
      stepu(v);
    }
  }

  // persist carry (owned cols only)
  if (owner) *(float2*)(cws + col0) = make_float2(c0, c1);

  if (t_begin + tc >= T) {  // last chunk: la[b] = alpha[ml-1][tl-1]
    int li = tl - 1;
    int w_own = (li < 128) ? 0 : ((li >> 6) - 1);
    if (wave == w_own) {
      int local = li - 64 * w_own;
      float v = (local & 1) ? c1 : c0;
      float lav = __shfl(v, local >> 1);
      if (lane == 0) la_ws[b] = lav;
    }
  }
}

__global__ __launch_bounds__(64) void reduce_kernel(const float* __restrict__ la_ws,
                                                    float* __restrict__ out) {
  int lane = threadIdx.x;
  float v = (lane < B) ? la_ws[lane] : 0.f;
#pragma unroll
  for (int s = 32; s > 0; s >>= 1) v += __shfl_down(v, s);
  if (lane == 0) out[0] = -v * (1.0f / (float)B);
}

extern "C" void kernel_launch(void* const* d_in, const int* in_sizes, int n_in,
                              void* d_out, int out_size, void* d_ws, size_t ws_size,
                              hipStream_t stream) {
  const float* mu_sigma = (const float*)d_in[0];
  const float* melspec  = (const float*)d_in[1];
  const int*   text_len = (const int*)d_in[2];
  const int*   mel_len  = (const int*)d_in[3];
  float* out = (float*)d_out;

  char* ws = (char*)d_ws;
  size_t off = 0;
  u16* Wfrag = (u16*)(ws + off);         off += (size_t)B * KDIM * L * 2;      // 5.2 MB
  float* biasv = (float*)(ws + off);     off += (size_t)B * L * 4;
  float* carry_ws = (float*)(ws + off);  off += (size_t)B * L * 4;
  float* la_ws = (float*)(ws + off);     off += 256;
  u16* Xfrag = (u16*)(ws + off);         off += (size_t)B * KDIM * T * 2;      // 21 MB
  u16* logpT = (u16*)(ws + off);
  size_t avail = (ws_size > off) ? (ws_size - off) : 0;
  size_t per_t = (size_t)B * L * 2;  // bytes per t-slice across all b (bf16)
  long long tcl = (long long)(avail / per_t);
  int Tc = (tcl > T) ? T : (int)tcl;
  Tc &= ~63;
  if (Tc < 64) return;  // insufficient workspace (not expected)

  prep_kernel<<<dim3((B * L + 255) / 256), 256, 0, stream>>>(mu_sigma, Wfrag, biasv);
  xprep_kernel<<<dim3((B * 10 * T) / 256), 256, 0, stream>>>(melspec, Xfrag);

  for (int t_begin = 0; t_begin < T; t_begin += Tc) {
    int tc = (T - t_begin < Tc) ? (T - t_begin) : Tc;
    dim3 grid(tc / 64, L / 128, B);
    gemm_logp<<<grid, 256, 0, stream>>>(Xfrag, Wfrag, biasv, mel_len, text_len,
                                        logpT, t_begin, tc);
    scan_kernel<<<dim3(B), 448, 0, stream>>>(logpT, mel_len, text_len, carry_ws,
                                             la_ws, t_begin, tc);
  }
  reduce_kernel<<<1, 64, 0, stream>>>(la_ws, out);
}